// Round 15
// baseline (685.473 us; speedup 1.0000x reference)
//
#include <hip/hip_runtime.h>
#include <hip/hip_bf16.h>
#include <utility>

#define BB 16
#define CC 16
#define HH 384
#define WW 384
#define HWSZ (HH*WW)
#define CHW (CC*HWSZ)
#define NPIX (BB*CHW)

#define FT 768             // 16 channels x 48 col-groups
#define ROWS 12            // rows per block -> 32x16 = 512 blocks
#define HSEGS (HH/ROWS)
#define SROW 408           // LDS row: 8 pad | 384 | 16 pad (bf16 elems)
#define NBUF 8             // 2 groups x 4 rows

typedef unsigned short ushortT;
template<int N> using ic = std::integral_constant<int, N>;

// ---- bf16 helpers ---------------------------------------------------------
__device__ __forceinline__ void unpk2(unsigned u, float& lo, float& hi) {
    union { unsigned u; float f; } a, b;
    a.u = u << 16; b.u = u & 0xFFFF0000u;
    lo = a.f; hi = b.f;
}
__device__ __forceinline__ unsigned pk2(float lo, float hi) {
    __hip_bfloat162 h = __float22bfloat162_rn(make_float2(lo, hi));
    union { __hip_bfloat162 h; unsigned u; } c; c.h = h;
    return c.u;
}
__device__ __forceinline__ void unpk8(const uint4& q, float* v) {
    unpk2(q.x, v[0], v[1]); unpk2(q.y, v[2], v[3]);
    unpk2(q.z, v[4], v[5]); unpk2(q.w, v[6], v[7]);
}
__device__ __forceinline__ uint4 pk8(const float* v) {
    uint4 q;
    q.x = pk2(v[0], v[1]); q.y = pk2(v[2], v[3]);
    q.z = pk2(v[4], v[5]); q.w = pk2(v[6], v[7]);
    return q;
}
template<int CTRL>
__device__ __forceinline__ float dpp_f(float x) {
    union { float f; int i; } c; c.f = x;
    union { int i; float f; } r;
    r.i = __builtin_amdgcn_update_dpp(0, c.i, CTRL, 0xF, 0xF, true);
    return r.f;
}

// ---------------------------------------------------------------------------
// Fused CRF step, 4-row groups: [C(prev grp) || A(cur grp)] bar [B(cur grp)]
// bar.  6 barriers per 12-row block (R9 had 24).  8 LDS row-buffers (104 KB),
// W[16] cyclic rolling t-window with constexpr slot indices.
//  MODE 0: in0 = x0 (f32); emits x0b (bf16) and t0.
//  MODE 1: in0 = t_n (bf16) + x0b; emits t_{n+1}.
//  MODE 2: in0 = t_4 (bf16) + x0b; emits log_softmax(x5) f32.
// ---------------------------------------------------------------------------
template<int MODE>
__global__ __launch_bounds__(FT, 3) void k_fused(
    const void* __restrict__ in0, const ushortT* __restrict__ x0b,
    void* __restrict__ outp, ushortT* __restrict__ x0b_out,
    const float* __restrict__ spacings, const float* __restrict__ invtheta,
    const float* __restrict__ swp)
{
    __shared__ ushortT xp[NBUF][CC][SROW];         // 104448 B
    __shared__ __align__(16) float l_lds[4][WW];   // MODE 2 only

    const int t  = threadIdx.x;
    const int b  = blockIdx.y;
    const int h0 = blockIdx.x * ROWS;

    {   // zero pads: 8 buf x 16 ch x 12 u32-slots = 1536; 768 threads x 2
#pragma unroll
        for (int z = 0; z < 2; ++z) {
            const int idx = t + z * FT;
            const int buf = idx / (CC * 12);
            const int rem = idx - buf * (CC * 12);
            const int c = rem / 12, s = rem - (rem / 12) * 12;
            const int e = (s < 4) ? (2 * s) : (392 + 2 * (s - 4));
            *(unsigned*)&xp[buf][c][e] = 0u;
        }
    }

    const float sw  = swp[0];
    const float sch = spacings[b * 2 + 0] * invtheta[0];   // H axis
    const float scw = spacings[b * 2 + 1] * invtheta[1];   // W axis
    float kh[5], kw[5];                                    // symmetric taps
#pragma unroll
    for (int j = 0; j < 5; ++j) {
        float dh = sch * (float)(j - 5); kh[j] = __expf(-0.5f * dh * dh);
        float dw = scw * (float)(j - 5); kw[j] = __expf(-0.5f * dw * dw);
    }

    const int ca = t / 48, ga = t - (t / 48) * 48;   // A/C identity
    const int cp = t >> 2, qq = t & 3;               // B identity

    const size_t cbase = (size_t)b * CHW + (size_t)ca * HWSZ + (size_t)ga * 8;
    const uint4 z4 = make_uint4(0u, 0u, 0u, 0u);

    // rolling t-window: slot s holds row h0-5+s (cyclic mod 16), packed bf16
    uint4 W[16];
    if (MODE >= 1) {
        const ushortT* tin = (const ushortT*)in0;
#pragma unroll
        for (int s = 0; s < 14; ++s) {
            const int r = h0 + s - 5;
            W[s] = ((unsigned)r < HH) ? *(const uint4*)(tin + cbase + (size_t)r * WW) : z4;
        }
        W[14] = z4; W[15] = z4;
    }

    __syncthreads();   // pads visible

    auto B_row = [&](int buf, int r) {
        float xa[4], xb[4];
#pragma unroll
        for (int i = 0; i < 4; ++i) {
            const unsigned u = *(const unsigned*)&xp[buf][qq * 4 + i][8 + 2 * cp];
            unpk2(u, xa[i], xb[i]);
        }
        float m0 = fmaxf(fmaxf(xa[0], xa[1]), fmaxf(xa[2], xa[3]));
        float m1 = fmaxf(fmaxf(xb[0], xb[1]), fmaxf(xb[2], xb[3]));
        m0 = fmaxf(m0, dpp_f<0xB1>(m0)); m0 = fmaxf(m0, dpp_f<0x4E>(m0));
        m1 = fmaxf(m1, dpp_f<0xB1>(m1)); m1 = fmaxf(m1, dpp_f<0x4E>(m1));
        float e0[4], e1[4], s0 = 0.f, s1 = 0.f;
#pragma unroll
        for (int i = 0; i < 4; ++i) {
            e0[i] = __expf(xa[i] - m0); s0 += e0[i];
            e1[i] = __expf(xb[i] - m1); s1 += e1[i];
        }
        s0 += dpp_f<0xB1>(s0); s0 += dpp_f<0x4E>(s0);
        s1 += dpp_f<0xB1>(s1); s1 += dpp_f<0x4E>(s1);
        if (MODE <= 1) {
            const float i0 = 1.0f / s0, i1 = 1.0f / s1;
#pragma unroll
            for (int i = 0; i < 4; ++i)
                *(unsigned*)&xp[buf][qq * 4 + i][8 + 2 * cp] = pk2(e0[i] * i0, e1[i] * i1);
        } else {
            if (qq == 0) {
                l_lds[r][2 * cp]     = m0 + __logf(s0);
                l_lds[r][2 * cp + 1] = m1 + __logf(s1);
            }
        }
    };

    auto C_row = [&](int h, int buf, int r) {
        if (MODE <= 1) {
            const uint4 q0 = *(const uint4*)&xp[buf][ca][ga * 8];
            const uint4 q1 = *(const uint4*)&xp[buf][ca][ga * 8 + 8];
            const uint4 q2 = *(const uint4*)&xp[buf][ca][ga * 8 + 16];
            float w[24];
            unpk8(q0, w); unpk8(q1, w + 8); unpk8(q2, w + 16);
            float o[8];
#pragma unroll
            for (int k = 0; k < 8; ++k) {
                float a = 0.f;
#pragma unroll
                for (int j = 0; j < 5; ++j)
                    a = fmaf(kw[j], w[k + 3 + j] + w[k + 13 - j], a);
                o[k] = a;
            }
            *(uint4*)((ushortT*)outp + cbase + (size_t)h * WW) = pk8(o);
        } else {
            const uint4 xq = *(const uint4*)&xp[buf][ca][8 + ga * 8];
            float xv[8]; unpk8(xq, xv);
            const float4 l0 = *(const float4*)&l_lds[r][ga * 8];
            const float4 l1 = *(const float4*)&l_lds[r][ga * 8 + 4];
            float* op = (float*)outp + cbase + (size_t)h * WW;
            *(float4*)op       = make_float4(xv[0]-l0.x, xv[1]-l0.y, xv[2]-l0.z, xv[3]-l0.w);
            *(float4*)(op + 4) = make_float4(xv[4]-l1.x, xv[5]-l1.y, xv[6]-l1.z, xv[7]-l1.w);
        }
    };

    // ConvH for block-row i (0..11): slots (i..i+10) mod 16, constexpr.
    auto A_row = [&](auto Ic, int buf, const uint4& uq) {
        constexpr int i = decltype(Ic)::value;
        float acc[8];
#pragma unroll
        for (int k = 0; k < 8; ++k) acc[k] = 0.f;
#pragma unroll
        for (int j = 0; j < 5; ++j) {
            const int sa = (i + j) % 16;         // constexpr-folded
            const int sb = (i + 10 - j) % 16;
            float e1[8], e2[8];
            unpk8(W[sa], e1); unpk8(W[sb], e2);
            const float kj = kh[j];
#pragma unroll
            for (int k = 0; k < 8; ++k)
                acc[k] = fmaf(kj, e1[k] + e2[k], acc[k]);
        }
        float uu[8]; unpk8(uq, uu);
        float xv[8];
#pragma unroll
        for (int k = 0; k < 8; ++k) xv[k] = fmaf(sw, acc[k], uu[k]);
        *(uint4*)&xp[buf][ca][8 + ga * 8] = pk8(xv);
    };

    auto A_row_m0 = [&](int h, int buf) {
        const float* xf = (const float*)in0;
        const float4 A0 = *(const float4*)(xf + cbase + (size_t)h * WW);
        const float4 A1 = *(const float4*)(xf + cbase + (size_t)h * WW + 4);
        float v[8] = {A0.x, A0.y, A0.z, A0.w, A1.x, A1.y, A1.z, A1.w};
        const uint4 q = pk8(v);
        *(uint4*)(x0b_out + cbase + (size_t)h * WW) = q;
        *(uint4*)&xp[buf][ca][8 + ga * 8] = q;
    };

    auto group = [&](auto Gc) {
        constexpr int g = decltype(Gc)::value;
        const int h = h0 + 4 * g;
        constexpr int bufA = (g & 1) * 4;
        constexpr int bufC = ((g & 1) ^ 1) * 4;

        if (MODE == 0) {
            if (g > 0) {
#pragma unroll
                for (int k = 0; k < 4; ++k) C_row(h - 4 + k, bufC + k, k);
            }
#pragma unroll
            for (int k = 0; k < 4; ++k) A_row_m0(h + k, bufA + k);
        } else {
            const ushortT* tin = (const ushortT*)in0;
            // issue all loads first: x0b rows (this group) + t rows (next group)
            uint4 uq[4];
#pragma unroll
            for (int k = 0; k < 4; ++k)
                uq[k] = *(const uint4*)(x0b + cbase + (size_t)(h + k) * WW);
            uint4 nt[4] = {z4, z4, z4, z4};
            if (g < 2) {
#pragma unroll
                for (int k = 0; k < 4; ++k) {
                    const int r = h + 9 + k;
                    if (r < HH) nt[k] = *(const uint4*)(tin + cbase + (size_t)r * WW);
                }
            }
            if (g > 0) {
#pragma unroll
                for (int k = 0; k < 4; ++k) C_row(h - 4 + k, bufC + k, k);
            }
            A_row(ic<4 * g + 0>{}, bufA + 0, uq[0]);
            A_row(ic<4 * g + 1>{}, bufA + 1, uq[1]);
            A_row(ic<4 * g + 2>{}, bufA + 2, uq[2]);
            A_row(ic<4 * g + 3>{}, bufA + 3, uq[3]);
            if (g < 2) {   // commit after A consumed the old slot contents
#pragma unroll
                for (int k = 0; k < 4; ++k) W[(4 * g + 14 + k) % 16] = nt[k];
            }
        }
        __syncthreads();
        B_row(bufA + 0, 0); B_row(bufA + 1, 1);
        B_row(bufA + 2, 2); B_row(bufA + 3, 3);
        __syncthreads();
    };

    group(ic<0>{}); group(ic<1>{}); group(ic<2>{});

    // epilogue: C of group 2 (bufs 0..3)
#pragma unroll
    for (int k = 0; k < 4; ++k) C_row(h0 + 8 + k, k, k);
}

// ---------------------------------------------------------------------------
extern "C" void kernel_launch(void* const* d_in, const int* in_sizes, int n_in,
                              void* d_out, int out_size, void* d_ws, size_t ws_size,
                              hipStream_t stream)
{
    const float* x0   = (const float*)d_in[0];  // (B,C,H,W) f32
    const float* spac = (const float*)d_in[1];  // (B,2)
    const float* sw   = (const float*)d_in[2];  // scalar
    const float* it   = (const float*)d_in[3];  // (2,)

    ushortT* tA  = (ushortT*)d_ws;              // 75.5 MB
    ushortT* tB  = tA + (size_t)NPIX;           // 75.5 MB
    ushortT* x0b = tB + (size_t)NPIX;           // 75.5 MB
    float*   out = (float*)d_out;

    dim3 gf(HSEGS, BB);   // (32,16) = 512 blocks
    dim3 bf(FT);

    // iter 1: t0 = ConvW(softmax(x0)); also emits x0b
    k_fused<0><<<gf, bf, 0, stream>>>(x0, nullptr, tA, x0b, spac, it, sw);
    // iters 2..5: t_{n+1} = ConvW(softmax(x0b + sw*ConvH(t_n)))
    k_fused<1><<<gf, bf, 0, stream>>>(tA, x0b, tB, nullptr, spac, it, sw);
    k_fused<1><<<gf, bf, 0, stream>>>(tB, x0b, tA, nullptr, spac, it, sw);
    k_fused<1><<<gf, bf, 0, stream>>>(tA, x0b, tB, nullptr, spac, it, sw);
    k_fused<1><<<gf, bf, 0, stream>>>(tB, x0b, tA, nullptr, spac, it, sw);
    // final: out = log_softmax(x0b + sw*ConvH(t4))
    k_fused<2><<<gf, bf, 0, stream>>>(tA, x0b, out, nullptr, spac, it, sw);
}

// Round 16
// 430.762 us; speedup vs baseline: 1.5913x; 1.5913x over previous
//
#include <hip/hip_runtime.h>
#include <hip/hip_bf16.h>
#include <utility>

#define BB 16
#define CC 16
#define HH 384
#define WW 384
#define HWSZ (HH*WW)
#define CHW (CC*HWSZ)
#define NPIX (BB*CHW)

#define FT 768             // 16 channels x 48 col-groups
#define ROWS 12            // rows per block -> 32x16 = 512 blocks
#define HSEGS (HH/ROWS)
#define PROW 456           // padded LDS row in u16: 204 words + 6x4 pad words = 228 w

typedef unsigned short ushortT;
template<int N> using ic = std::integral_constant<int, N>;

// bank-deconflict address map: logical u16 idx -> physical u16 idx.
// word w -> w + (w>>5)*4  (4-word pad every 32 words; keeps 16B alignment,
// b128 blocks never cross a 32-word boundary since all accesses are 4w-aligned)
__device__ __forceinline__ int swz(int u) {
    const int w = u >> 1;
    return ((w + ((w >> 5) << 2)) << 1) | (u & 1);
}

// ---- bf16 helpers ---------------------------------------------------------
__device__ __forceinline__ void unpk2(unsigned u, float& lo, float& hi) {
    union { unsigned u; float f; } a, b;
    a.u = u << 16; b.u = u & 0xFFFF0000u;
    lo = a.f; hi = b.f;
}
__device__ __forceinline__ unsigned pk2(float lo, float hi) {
    __hip_bfloat162 h = __float22bfloat162_rn(make_float2(lo, hi));
    union { __hip_bfloat162 h; unsigned u; } c; c.h = h;
    return c.u;
}
__device__ __forceinline__ void unpk8(const uint4& q, float* v) {
    unpk2(q.x, v[0], v[1]); unpk2(q.y, v[2], v[3]);
    unpk2(q.z, v[4], v[5]); unpk2(q.w, v[6], v[7]);
}
__device__ __forceinline__ uint4 pk8(const float* v) {
    uint4 q;
    q.x = pk2(v[0], v[1]); q.y = pk2(v[2], v[3]);
    q.z = pk2(v[4], v[5]); q.w = pk2(v[6], v[7]);
    return q;
}
template<int CTRL>
__device__ __forceinline__ float dpp_f(float x) {
    union { float f; int i; } c; c.f = x;
    union { int i; float f; } r;
    r.i = __builtin_amdgcn_update_dpp(0, c.i, CTRL, 0xF, 0xF, true);
    return r.f;
}

// ---------------------------------------------------------------------------
// Fused CRF step (R9 structure + LDS bank-deconflict swizzle).
//  MODE 0: in0 = x0 (f32); emits x0b (bf16) and t0.
//  MODE 1: in0 = t_n (bf16) + x0b; emits t_{n+1}.
//  MODE 2: in0 = t_4 (bf16) + x0b; emits log_softmax(x5) f32.
// ---------------------------------------------------------------------------
template<int MODE>
__global__ __launch_bounds__(FT, 3) void k_fused(
    const void* __restrict__ in0, const ushortT* __restrict__ x0b,
    void* __restrict__ outp, ushortT* __restrict__ x0b_out,
    const float* __restrict__ spacings, const float* __restrict__ invtheta,
    const float* __restrict__ swp)
{
    __shared__ ushortT xp[4][CC][PROW];          // 58368 B, 4-row ring
    __shared__ __align__(16) float l_lds[2][WW]; // MODE 2 only

    const int t  = threadIdx.x;
    const int b  = blockIdx.y;
    const int h0 = blockIdx.x * ROWS;

    {   // zero pads: 4 buf x 16 ch x 12 u32-slots = 768 threads, one each
        const int buf = t / (CC * 12);
        const int rem = t - buf * (CC * 12);
        const int c = rem / 12, s = rem - (rem / 12) * 12;
        const int e = (s < 4) ? (2 * s) : (392 + 2 * (s - 4));
        *(unsigned*)&xp[buf][c][swz(e)] = 0u;
    }

    const float sw  = swp[0];
    const float sch = spacings[b * 2 + 0] * invtheta[0];   // H axis
    const float scw = spacings[b * 2 + 1] * invtheta[1];   // W axis
    float kh[5], kw[5];                                    // symmetric taps
#pragma unroll
    for (int j = 0; j < 5; ++j) {
        float dh = sch * (float)(j - 5); kh[j] = __expf(-0.5f * dh * dh);
        float dw = scw * (float)(j - 5); kw[j] = __expf(-0.5f * dw * dw);
    }

    const int ca = t / 48, ga = t - (t / 48) * 48;   // A/C identity
    const int cp = t >> 2, qq = t & 3;               // B identity

    const size_t cbase = (size_t)b * CHW + (size_t)ca * HWSZ + (size_t)ga * 8;
    const uint4 z4 = make_uint4(0u, 0u, 0u, 0u);

    // precomputed swizzled offsets (wave-uniform-free, few SGPR/VGPRs)
    const int oA  = swz(8 + ga * 8);     // A store / MODE2 C read
    const int oC0 = swz(ga * 8);         // C read 0
    const int oC1 = swz(ga * 8 + 8);     // C read 1
    const int oC2 = swz(ga * 8 + 16);    // C read 2
    const int oB  = swz(8 + 2 * cp);     // B read/write

    // rolling t-window: slot s holds t-row (h0-5+s), cyclic; packed bf16
    uint4 W[12];
    if (MODE >= 1) {
        const ushortT* tin = (const ushortT*)in0;
#pragma unroll
        for (int j = 0; j < 12; ++j) {
            const int r = h0 + j - 5;
            W[j] = ((unsigned)r < HH) ? *(const uint4*)(tin + cbase + (size_t)r * WW) : z4;
        }
    }

    __syncthreads();   // pads visible

    auto B_row = [&](int buf, int r) {
        float xa[4], xb[4];
#pragma unroll
        for (int i = 0; i < 4; ++i) {
            const unsigned u = *(const unsigned*)&xp[buf][qq * 4 + i][oB];
            unpk2(u, xa[i], xb[i]);
        }
        float m0 = fmaxf(fmaxf(xa[0], xa[1]), fmaxf(xa[2], xa[3]));
        float m1 = fmaxf(fmaxf(xb[0], xb[1]), fmaxf(xb[2], xb[3]));
        m0 = fmaxf(m0, dpp_f<0xB1>(m0)); m0 = fmaxf(m0, dpp_f<0x4E>(m0));
        m1 = fmaxf(m1, dpp_f<0xB1>(m1)); m1 = fmaxf(m1, dpp_f<0x4E>(m1));
        float e0[4], e1[4], s0 = 0.f, s1 = 0.f;
#pragma unroll
        for (int i = 0; i < 4; ++i) {
            e0[i] = __expf(xa[i] - m0); s0 += e0[i];
            e1[i] = __expf(xb[i] - m1); s1 += e1[i];
        }
        s0 += dpp_f<0xB1>(s0); s0 += dpp_f<0x4E>(s0);
        s1 += dpp_f<0xB1>(s1); s1 += dpp_f<0x4E>(s1);
        if (MODE <= 1) {
            const float i0 = 1.0f / s0, i1 = 1.0f / s1;
#pragma unroll
            for (int i = 0; i < 4; ++i)
                *(unsigned*)&xp[buf][qq * 4 + i][oB] = pk2(e0[i] * i0, e1[i] * i1);
        } else {
            if (qq == 0) {
                l_lds[r][2 * cp]     = m0 + __logf(s0);
                l_lds[r][2 * cp + 1] = m1 + __logf(s1);
            }
        }
    };

    auto C_row = [&](int h, int buf, int r) {
        if (MODE <= 1) {
            const uint4 q0 = *(const uint4*)&xp[buf][ca][oC0];
            const uint4 q1 = *(const uint4*)&xp[buf][ca][oC1];
            const uint4 q2 = *(const uint4*)&xp[buf][ca][oC2];
            float w[24];
            unpk8(q0, w); unpk8(q1, w + 8); unpk8(q2, w + 16);
            float o[8];
#pragma unroll
            for (int k = 0; k < 8; ++k) {
                float a = 0.f;
#pragma unroll
                for (int j = 0; j < 5; ++j)
                    a = fmaf(kw[j], w[k + 3 + j] + w[k + 13 - j], a);
                o[k] = a;
            }
            *(uint4*)((ushortT*)outp + cbase + (size_t)h * WW) = pk8(o);
        } else {
            const uint4 xq = *(const uint4*)&xp[buf][ca][oA];
            float xv[8]; unpk8(xq, xv);
            const float4 l0 = *(const float4*)&l_lds[r][ga * 8];
            const float4 l1 = *(const float4*)&l_lds[r][ga * 8 + 4];
            float* op = (float*)outp + cbase + (size_t)h * WW;
            *(float4*)op       = make_float4(xv[0]-l0.x, xv[1]-l0.y, xv[2]-l0.z, xv[3]-l0.w);
            *(float4*)(op + 4) = make_float4(xv[4]-l1.x, xv[5]-l1.y, xv[6]-l1.z, xv[7]-l1.w);
        }
    };

    // ConvH row from static window slots + x0b row -> LDS
    auto A_row = [&](auto K0c, int buf, const uint4& uq) {
        constexpr int k0 = decltype(K0c)::value;
        float acc[8];
#pragma unroll
        for (int k = 0; k < 8; ++k) acc[k] = 0.f;
#pragma unroll
        for (int j = 0; j < 5; ++j) {
            const int sa = (k0 + j) % 12;        // folds: k0 constexpr, j unrolled
            const int sb = (k0 + 10 - j) % 12;
            float e1[8], e2[8];
            unpk8(W[sa], e1); unpk8(W[sb], e2);
            const float kj = kh[j];
#pragma unroll
            for (int k = 0; k < 8; ++k)
                acc[k] = fmaf(kj, e1[k] + e2[k], acc[k]);
        }
        float uu[8]; unpk8(uq, uu);
        float xv[8];
#pragma unroll
        for (int k = 0; k < 8; ++k) xv[k] = fmaf(sw, acc[k], uu[k]);
        *(uint4*)&xp[buf][ca][oA] = pk8(xv);
    };

    auto A_row_m0 = [&](int h, int buf) {
        const float* xf = (const float*)in0;
        const float4 A0 = *(const float4*)(xf + cbase + (size_t)h * WW);
        const float4 A1 = *(const float4*)(xf + cbase + (size_t)h * WW + 4);
        float v[8] = {A0.x, A0.y, A0.z, A0.w, A1.x, A1.y, A1.z, A1.w};
        const uint4 q = pk8(v);
        *(uint4*)(x0b_out + cbase + (size_t)h * WW) = q;
        *(uint4*)&xp[buf][ca][oA] = q;
    };

    auto pair_body = [&](auto Pc) {
        constexpr int p = decltype(Pc)::value;
        const int h  = h0 + 2 * p;
        constexpr int bA = 2 * (p & 1);
        constexpr int bC = 2 * ((p & 1) ^ 1);

        if (MODE == 0) {
            if (p > 0) { C_row(h - 2, bC, 0); C_row(h - 1, bC + 1, 1); }
            A_row_m0(h, bA); A_row_m0(h + 1, bA + 1);
        } else {
            const ushortT* tin = (const ushortT*)in0;
            const uint4 uq0 = *(const uint4*)(x0b + cbase + (size_t)h * WW);
            const uint4 uq1 = *(const uint4*)(x0b + cbase + (size_t)(h + 1) * WW);
            uint4 nt0 = z4, nt1 = z4;
            if (p < 5) {
                const int r0 = h + 7, r1 = h + 8;
                if (r0 < HH) nt0 = *(const uint4*)(tin + cbase + (size_t)r0 * WW);
                if (r1 < HH) nt1 = *(const uint4*)(tin + cbase + (size_t)r1 * WW);
            }
            if (p > 0) { C_row(h - 2, bC, 0); C_row(h - 1, bC + 1, 1); }
            A_row(ic<(2 * p) % 12>{},     bA,     uq0);
            A_row(ic<(2 * p + 1) % 12>{}, bA + 1, uq1);
            if (p < 5) {
                W[(2 * p) % 12]     = nt0;
                W[(2 * p + 1) % 12] = nt1;
            }
        }
        __syncthreads();
        B_row(bA, 0);
        B_row(bA + 1, 1);
        __syncthreads();
    };

    pair_body(ic<0>{}); pair_body(ic<1>{}); pair_body(ic<2>{});
    pair_body(ic<3>{}); pair_body(ic<4>{}); pair_body(ic<5>{});

    // epilogue: C of last pair (bufs 2,3)
    C_row(h0 + 10, 2, 0);
    C_row(h0 + 11, 3, 1);
}

// ---------------------------------------------------------------------------
extern "C" void kernel_launch(void* const* d_in, const int* in_sizes, int n_in,
                              void* d_out, int out_size, void* d_ws, size_t ws_size,
                              hipStream_t stream)
{
    const float* x0   = (const float*)d_in[0];  // (B,C,H,W) f32
    const float* spac = (const float*)d_in[1];  // (B,2)
    const float* sw   = (const float*)d_in[2];  // scalar
    const float* it   = (const float*)d_in[3];  // (2,)

    ushortT* tA  = (ushortT*)d_ws;              // 75.5 MB
    ushortT* tB  = tA + (size_t)NPIX;           // 75.5 MB
    ushortT* x0b = tB + (size_t)NPIX;           // 75.5 MB
    float*   out = (float*)d_out;

    dim3 gf(HSEGS, BB);   // (32,16) = 512 blocks
    dim3 bf(FT);

    // iter 1: t0 = ConvW(softmax(x0)); also emits x0b
    k_fused<0><<<gf, bf, 0, stream>>>(x0, nullptr, tA, x0b, spac, it, sw);
    // iters 2..5: t_{n+1} = ConvW(softmax(x0b + sw*ConvH(t_n)))
    k_fused<1><<<gf, bf, 0, stream>>>(tA, x0b, tB, nullptr, spac, it, sw);
    k_fused<1><<<gf, bf, 0, stream>>>(tB, x0b, tA, nullptr, spac, it, sw);
    k_fused<1><<<gf, bf, 0, stream>>>(tA, x0b, tB, nullptr, spac, it, sw);
    k_fused<1><<<gf, bf, 0, stream>>>(tB, x0b, tA, nullptr, spac, it, sw);
    // final: out = log_softmax(x0b + sw*ConvH(t4))
    k_fused<2><<<gf, bf, 0, stream>>>(tA, x0b, out, nullptr, spac, it, sw);
}

// Round 17
// 412.567 us; speedup vs baseline: 1.6615x; 1.0441x over previous
//
#include <hip/hip_runtime.h>
#include <hip/hip_bf16.h>
#include <utility>

#define BB 16
#define CC 16
#define HH 384
#define WW 384
#define HWSZ (HH*WW)
#define CHW (CC*HWSZ)
#define NPIX (BB*CHW)

#define FT 768             // 16 channels x 48 col-groups
#define ROWS 12            // rows per block -> 32x16 = 512 blocks
#define HSEGS (HH/ROWS)
#define SROW 408           // LDS row: 8 pad | 384 | 16 pad (bf16 elems)

typedef unsigned short ushortT;

// ---- bf16 helpers ---------------------------------------------------------
__device__ __forceinline__ void unpk2(unsigned u, float& lo, float& hi) {
    union { unsigned u; float f; } a, b;
    a.u = u << 16; b.u = u & 0xFFFF0000u;
    lo = a.f; hi = b.f;
}
// native RNE pack: compiler emits v_cvt_pk_bf16_f32
__device__ __forceinline__ unsigned pk2(float lo, float hi) {
    __hip_bfloat162 h = __float22bfloat162_rn(make_float2(lo, hi));
    union { __hip_bfloat162 h; unsigned u; } c; c.h = h;
    return c.u;
}
__device__ __forceinline__ void unpk8(const uint4& q, float* v) {
    unpk2(q.x, v[0], v[1]); unpk2(q.y, v[2], v[3]);
    unpk2(q.z, v[4], v[5]); unpk2(q.w, v[6], v[7]);
}
__device__ __forceinline__ uint4 pk8(const float* v) {
    uint4 q;
    q.x = pk2(v[0], v[1]); q.y = pk2(v[2], v[3]);
    q.z = pk2(v[4], v[5]); q.w = pk2(v[6], v[7]);
    return q;
}
// quad-perm DPP cross-lane (VALU pipe, not DS): 0xB1 = xor1, 0x4E = xor2
template<int CTRL>
__device__ __forceinline__ float dpp_f(float x) {
    union { float f; int i; } c; c.f = x;
    union { int i; float f; } r;
    r.i = __builtin_amdgcn_update_dpp(0, c.i, CTRL, 0xF, 0xF, true);
    return r.f;
}

// ---------------------------------------------------------------------------
// Fused CRF step, 2-row phases (the measured optimum configuration).
//  MODE 0: in0 = x0 (f32); emits x0b (bf16) and t0.
//  MODE 1: in0 = t_n (bf16) + x0b; emits t_{n+1}.
//  MODE 2: in0 = t_4 (bf16) + x0b; emits log_softmax(x5) f32.
// Per pair of rows: P1 = { C(prev pair) overlapped with A(cur pair) }, bar,
//                   P2 = { B softmax (u32 col-pairs + DPP quad reduce) }, bar.
// 4 LDS row-buffers; 12 barriers/block.
// ---------------------------------------------------------------------------
template<int MODE>
__global__ __launch_bounds__(FT) void k_fused(
    const void* __restrict__ in0, const ushortT* __restrict__ x0b,
    void* __restrict__ outp, ushortT* __restrict__ x0b_out,
    const float* __restrict__ spacings, const float* __restrict__ invtheta,
    const float* __restrict__ swp)
{
    __shared__ ushortT xp[4][CC][SROW];          // 52224 B
    __shared__ __align__(16) float l_lds[2][WW]; // MODE 2 only

    const int t  = threadIdx.x;
    const int b  = blockIdx.y;
    const int h0 = blockIdx.x * ROWS;

    {   // zero pads: 4 buf x 16 ch x 12 u32-slots = 768 threads, one each
        const int buf = t / (CC * 12);
        const int rem = t - buf * (CC * 12);
        const int c = rem / 12, s = rem - (rem / 12) * 12;
        const int e = (s < 4) ? (2 * s) : (392 + 2 * (s - 4));
        *(unsigned*)&xp[buf][c][e] = 0u;
    }

    const float sw  = swp[0];
    const float sch = spacings[b * 2 + 0] * invtheta[0];   // H axis
    const float scw = spacings[b * 2 + 1] * invtheta[1];   // W axis
    float kh[5], kw[5];                                    // symmetric taps
#pragma unroll
    for (int j = 0; j < 5; ++j) {
        float dh = sch * (float)(j - 5); kh[j] = __expf(-0.5f * dh * dh);
        float dw = scw * (float)(j - 5); kw[j] = __expf(-0.5f * dw * dw);
    }

    const int ca = t / 48, ga = t - (t / 48) * 48;   // A/C identity
    const int cp = t >> 2, qq = t & 3;               // B identity (col-pair, ch-quad)

    const size_t cbase = (size_t)b * CHW + (size_t)ca * HWSZ + (size_t)ga * 8;
    const uint4 z4 = make_uint4(0u, 0u, 0u, 0u);

    // 12-slot rolling window: W[j] = t-row (h-5+j), rows h..h+1 use [0..10]/[1..11]
    uint4 W[12];
    if (MODE >= 1) {
        const ushortT* tin = (const ushortT*)in0;
#pragma unroll
        for (int j = 0; j < 12; ++j) {
            const int r = h0 + j - 5;
            W[j] = ((unsigned)r < HH) ? *(const uint4*)(tin + cbase + (size_t)r * WW) : z4;
        }
    }

    __syncthreads();   // pads visible

    auto A_row_m0 = [&](int h, int buf) {
        const float* xf = (const float*)in0;
        const float4 A0 = *(const float4*)(xf + cbase + (size_t)h * WW);
        const float4 A1 = *(const float4*)(xf + cbase + (size_t)h * WW + 4);
        float v[8] = {A0.x, A0.y, A0.z, A0.w, A1.x, A1.y, A1.z, A1.w};
        const uint4 q = pk8(v);
        *(uint4*)(x0b_out + cbase + (size_t)h * WW) = q;
        *(uint4*)&xp[buf][ca][8 + ga * 8] = q;
    };

    auto A_row = [&](int o, int buf, uint4 uq) {     // ConvH from W[o..o+10] + add
        float acc[8];
#pragma unroll
        for (int k = 0; k < 8; ++k) acc[k] = 0.f;
#pragma unroll
        for (int j = 0; j < 5; ++j) {                // symmetric pairs (o+j, o+10-j)
            float e1[8], e2[8];
            unpk8(W[o + j], e1); unpk8(W[o + 10 - j], e2);
            const float kj = kh[j];
#pragma unroll
            for (int k = 0; k < 8; ++k) acc[k] = fmaf(kj, e1[k] + e2[k], acc[k]);
        }
        float uu[8]; unpk8(uq, uu);
        float xv[8];
#pragma unroll
        for (int k = 0; k < 8; ++k) xv[k] = fmaf(sw, acc[k], uu[k]);
        *(uint4*)&xp[buf][ca][8 + ga * 8] = pk8(xv);
    };

    auto B_row = [&](int buf, int r) {
        float xa[4], xb[4];
#pragma unroll
        for (int i = 0; i < 4; ++i) {
            const unsigned u = *(const unsigned*)&xp[buf][qq * 4 + i][8 + 2 * cp];
            unpk2(u, xa[i], xb[i]);
        }
        float m0 = fmaxf(fmaxf(xa[0], xa[1]), fmaxf(xa[2], xa[3]));
        float m1 = fmaxf(fmaxf(xb[0], xb[1]), fmaxf(xb[2], xb[3]));
        m0 = fmaxf(m0, dpp_f<0xB1>(m0)); m0 = fmaxf(m0, dpp_f<0x4E>(m0));
        m1 = fmaxf(m1, dpp_f<0xB1>(m1)); m1 = fmaxf(m1, dpp_f<0x4E>(m1));
        float e0[4], e1[4], s0 = 0.f, s1 = 0.f;
#pragma unroll
        for (int i = 0; i < 4; ++i) {
            e0[i] = __expf(xa[i] - m0); s0 += e0[i];
            e1[i] = __expf(xb[i] - m1); s1 += e1[i];
        }
        s0 += dpp_f<0xB1>(s0); s0 += dpp_f<0x4E>(s0);
        s1 += dpp_f<0xB1>(s1); s1 += dpp_f<0x4E>(s1);
        if (MODE <= 1) {
            const float i0 = 1.0f / s0, i1 = 1.0f / s1;
#pragma unroll
            for (int i = 0; i < 4; ++i)
                *(unsigned*)&xp[buf][qq * 4 + i][8 + 2 * cp] = pk2(e0[i] * i0, e1[i] * i1);
        } else {
            if (qq == 0) {
                l_lds[r][2 * cp]     = m0 + __logf(s0);
                l_lds[r][2 * cp + 1] = m1 + __logf(s1);
            }
        }
    };

    auto C_row = [&](int h, int buf, int r) {
        if (MODE <= 1) {
            const uint4 q0 = *(const uint4*)&xp[buf][ca][ga * 8];
            const uint4 q1 = *(const uint4*)&xp[buf][ca][ga * 8 + 8];
            const uint4 q2 = *(const uint4*)&xp[buf][ca][ga * 8 + 16];
            float w[24];
            unpk8(q0, w); unpk8(q1, w + 8); unpk8(q2, w + 16);
            float o[8];
#pragma unroll
            for (int k = 0; k < 8; ++k) {
                float a = 0.f;
#pragma unroll
                for (int j = 0; j < 5; ++j)          // symmetric col pairs
                    a = fmaf(kw[j], w[k + 3 + j] + w[k + 13 - j], a);
                o[k] = a;
            }
            *(uint4*)((ushortT*)outp + cbase + (size_t)h * WW) = pk8(o);
        } else {
            const uint4 xq = *(const uint4*)&xp[buf][ca][8 + ga * 8];
            float xv[8]; unpk8(xq, xv);
            const float4 l0 = *(const float4*)&l_lds[r][ga * 8];
            const float4 l1 = *(const float4*)&l_lds[r][ga * 8 + 4];
            float* op = (float*)outp + cbase + (size_t)h * WW;
            *(float4*)op       = make_float4(xv[0]-l0.x, xv[1]-l0.y, xv[2]-l0.z, xv[3]-l0.w);
            *(float4*)(op + 4) = make_float4(xv[4]-l1.x, xv[5]-l1.y, xv[6]-l1.z, xv[7]-l1.w);
        }
    };

#pragma unroll
    for (int p = 0; p < 6; ++p) {
        const int h  = h0 + 2 * p;
        const int bA = 2 * (p & 1);
        const int bC = 2 * ((p & 1) ^ 1);

        // ---- P1: C(prev) overlapped with loads + A(cur) ----
        if (MODE == 0) {
            if (p > 0) { C_row(h - 2, bC, 0); C_row(h - 1, bC + 1, 1); }
            A_row_m0(h, bA); A_row_m0(h + 1, bA + 1);
        } else {
            const ushortT* tin = (const ushortT*)in0;
            const uint4 uq0 = *(const uint4*)(x0b + cbase + (size_t)h * WW);
            const uint4 uq1 = *(const uint4*)(x0b + cbase + (size_t)(h + 1) * WW);
            uint4 nt0 = z4, nt1 = z4;
            if (p < 5) {
                const int r0 = h + 7, r1 = h + 8;
                if (r0 < HH) nt0 = *(const uint4*)(tin + cbase + (size_t)r0 * WW);
                if (r1 < HH) nt1 = *(const uint4*)(tin + cbase + (size_t)r1 * WW);
            }
            if (p > 0) { C_row(h - 2, bC, 0); C_row(h - 1, bC + 1, 1); }
            A_row(0, bA,     uq0);
            A_row(1, bA + 1, uq1);
            if (p < 5) {
#pragma unroll
                for (int j = 0; j < 10; ++j) W[j] = W[j + 2];
                W[10] = nt0; W[11] = nt1;
            }
        }
        __syncthreads();

        // ---- P2: softmax both rows ----
        B_row(bA, 0);
        B_row(bA + 1, 1);
        __syncthreads();
    }
    // epilogue: C of last pair (bufs 2,3)
    C_row(h0 + 10, 2, 0);
    C_row(h0 + 11, 3, 1);
}

// ---------------------------------------------------------------------------
extern "C" void kernel_launch(void* const* d_in, const int* in_sizes, int n_in,
                              void* d_out, int out_size, void* d_ws, size_t ws_size,
                              hipStream_t stream)
{
    const float* x0   = (const float*)d_in[0];  // (B,C,H,W) f32
    const float* spac = (const float*)d_in[1];  // (B,2)
    const float* sw   = (const float*)d_in[2];  // scalar
    const float* it   = (const float*)d_in[3];  // (2,)

    ushortT* tA  = (ushortT*)d_ws;              // 75.5 MB
    ushortT* tB  = tA + (size_t)NPIX;           // 75.5 MB
    ushortT* x0b = tB + (size_t)NPIX;           // 75.5 MB
    float*   out = (float*)d_out;

    dim3 gf(HSEGS, BB);   // (32,16) = 512 blocks
    dim3 bf(FT);

    // iter 1: t0 = ConvW(softmax(x0)); also emits x0b
    k_fused<0><<<gf, bf, 0, stream>>>(x0, nullptr, tA, x0b, spac, it, sw);
    // iters 2..5: t_{n+1} = ConvW(softmax(x0b + sw*ConvH(t_n)))
    k_fused<1><<<gf, bf, 0, stream>>>(tA, x0b, tB, nullptr, spac, it, sw);
    k_fused<1><<<gf, bf, 0, stream>>>(tB, x0b, tA, nullptr, spac, it, sw);
    k_fused<1><<<gf, bf, 0, stream>>>(tA, x0b, tB, nullptr, spac, it, sw);
    k_fused<1><<<gf, bf, 0, stream>>>(tB, x0b, tA, nullptr, spac, it, sw);
    // final: out = log_softmax(x0b + sw*ConvH(t4))
    k_fused<2><<<gf, bf, 0, stream>>>(tA, x0b, out, nullptr, spac, it, sw);
}